// Round 3
// baseline (886.264 us; speedup 1.0000x reference)
//
#include <hip/hip_runtime.h>
#include <hip/hip_bf16.h>
#include <math.h>

typedef unsigned short u16;
typedef __bf16 bf16x8 __attribute__((ext_vector_type(8)));
typedef float f32x4 __attribute__((ext_vector_type(4)));

__device__ __forceinline__ float b2f(u16 u) {
  union { unsigned int i; float f; } v; v.i = ((unsigned int)u) << 16; return v.f;
}
__device__ __forceinline__ u16 f2b(float f) {
  union { float f; unsigned int i; } v; v.f = f;
  unsigned int x = v.i;
  return (u16)((x + 0x7fffu + ((x >> 16) & 1u)) >> 16);
}
// dual-dtype scalar load: isf=1 -> f32, isf=0 -> bf16
__device__ __forceinline__ float ldx(const void* p, size_t i, int isf) {
  return isf ? ((const float*)p)[i] : b2f(((const u16*)p)[i]);
}

// ---------------- kernel 0: dtype detect (f32 vs bf16) ----------------
__global__ void k_detect(const void* __restrict__ query, int* __restrict__ flag) {
  int t = threadIdx.x;  // 64 threads
  float v = ((const float*)query)[t];   // 256 B read, safe either dtype
  int ok = (v == v && fabsf(v) < 100.f && fabsf(v) > 1e-4f) ? 1 : 0;
  unsigned long long m = __ballot(ok);
  if (t == 0) flag[0] = (__popcll(m) >= 32) ? 1 : 0;
}

// ---------------- kernel 1: W_in (512x512) -> bf16 WT[j][c] ----------------
__global__ void k_transpose(const void* __restrict__ Win, u16* __restrict__ WT,
                            const int* __restrict__ flag) {
  int isf = flag[0];
  int gid = blockIdx.x * 256 + threadIdx.x;      // 0..262143
  int j = gid >> 9, c = gid & 511;
  WT[j * 512 + c] = f2b(ldx(Win, (size_t)c * 512 + j, isf));
}

// ---------------- kernel 2: per-batch q prep -> u[b][c][n], c0[b][n] ----------------
__global__ __launch_bounds__(256) void k_qprep(
    const void* __restrict__ query, const void* __restrict__ Wq, const void* __restrict__ bq,
    const void* __restrict__ Wkv, const void* __restrict__ bkv,
    const void* __restrict__ g_q, const void* __restrict__ be_q,
    float* __restrict__ u_out, float* __restrict__ c0_out,
    const int* __restrict__ flag) {
  int isf = flag[0];
  int b = blockIdx.x, t = threadIdx.x;
  __shared__ float qf[512];
  __shared__ float qr[512];
  __shared__ float red[8];
  __shared__ float stats[2];

  float s = 0.f, ss = 0.f;
  for (int k = 0; k < 2; k++) {
    int c = t + 256 * k;
    float v = ldx(query, (size_t)b * 512 + c, isf);
    qf[c] = v; s += v; ss += v * v;
  }
  for (int off = 32; off; off >>= 1) { s += __shfl_xor(s, off); ss += __shfl_xor(ss, off); }
  int wid = t >> 6, lane = t & 63;
  if (lane == 0) { red[wid * 2] = s; red[wid * 2 + 1] = ss; }
  __syncthreads();
  if (t == 0) {
    float S = 0.f, SS = 0.f;
    for (int w = 0; w < 4; w++) { S += red[w * 2]; SS += red[w * 2 + 1]; }
    float mu = S / 512.f;
    float var = SS / 512.f - mu * mu;
    stats[0] = mu; stats[1] = rsqrtf(var + 1e-5f);
  }
  __syncthreads();
  float mu = stats[0], rstd = stats[1];
  for (int k = 0; k < 2; k++) {
    int c = t + 256 * k;
    qf[c] = (qf[c] - mu) * rstd * ldx(g_q, c, isf) + ldx(be_q, c, isf);
  }
  __syncthreads();
  for (int k = 0; k < 2; k++) {
    int j = t + 256 * k;
    float acc = ldx(bq, j, isf);
    if (isf) {
      const float* wp = (const float*)Wq + j;
      for (int c = 0; c < 512; c++) acc += qf[c] * wp[(size_t)c * 512];
    } else {
      const u16* wp = (const u16*)Wq + j;
      for (int c = 0; c < 512; c++) acc += qf[c] * b2f(wp[(size_t)c * 512]);
    }
    qr[j] = acc;
  }
  __syncthreads();
  // u[b][c][n] = sum_d Wkv[c][n*64+d] * qr[n*64+d]
  for (int k = 0; k < 16; k++) {
    int e = t + 256 * k;
    int c = e >> 3, n = e & 7;
    size_t base = (size_t)c * 1024 + n * 64;
    const float* qp = qr + n * 64;
    float acc = 0.f;
    if (isf) {
      const float* wp = (const float*)Wkv + base;
      #pragma unroll 8
      for (int d = 0; d < 64; d++) acc += wp[d] * qp[d];
    } else {
      const u16* wp = (const u16*)Wkv + base;
      #pragma unroll 8
      for (int d = 0; d < 64; d++) acc += b2f(wp[d]) * qp[d];
    }
    u_out[(size_t)(b * 512 + c) * 8 + n] = acc;
  }
  if (t < 8) {
    float acc = 0.f;
    for (int d = 0; d < 64; d++) acc += ldx(bkv, t * 64 + d, isf) * qr[t * 64 + d];
    c0_out[b * 8 + t] = acc;
  }
}

// ---------------- kernel 3: fused m-GEMM + relu + LN + scores + r + V-matvec ----------------
// grid (16, 32), 512 thr (8 waves). Each block: 4 row-tiles of 64 rows x 512 cols.
#define LDA 40
#define LDB 40
__global__ __launch_bounds__(512) void k_main(
    const void* __restrict__ mem, const u16* __restrict__ WT, const void* __restrict__ b_in,
    const void* __restrict__ g_in, const void* __restrict__ be_in, const void* __restrict__ ior,
    const float* __restrict__ u_in, const float* __restrict__ c0_in,
    const void* __restrict__ Wkv, const void* __restrict__ bkv,
    float* __restrict__ x_acc, const int* __restrict__ flag) {
  int isf = flag[0];
  int blk = blockIdx.x;           // 0..15 (4 row-tiles each)
  int b   = blockIdx.y;           // 0..31
  int t = threadIdx.x;
  int w = t >> 6, lane = t & 63;
  int l15 = lane & 15, q = lane >> 4;

  // LDS map (bytes), total 62496 (< 64 KB):
  //   Ab    [0, 5120)        64x40 bf16
  //   Bb    [5120, 46080)    512x40 bf16  (K-loop phase)
  //     epilogue overlays: sc [5120,21504), rowred [21504,25600),
  //                        mu_rstd [25600,26112), a_lds [26112,28160)
  //   A_l   [46080, 46112)   8 f32 (persistent)
  //   r_lds [46112, 62496)   8x512 f32 (persistent accumulator)
  __shared__ __align__(16) char smem[62496];
  u16*  Ab      = (u16*)smem;
  u16*  Bb      = (u16*)(smem + 5120);
  float* sc     = (float*)(smem + 5120);
  float* rowred = (float*)(smem + 21504);
  float* mu_rstd= (float*)(smem + 25600);
  float* a_lds  = (float*)(smem + 26112);
  float* A_l    = (float*)(smem + 46080);
  float* r_lds  = (float*)(smem + 46112);

  // one-time init
  #pragma unroll
  for (int n = 0; n < 8; n++) r_lds[t * 8 + n] = 0.f;
  if (t < 8) A_l[t] = 0.f;

  int colj[4];
  float gv[4], bev[4], binv[4];
  float uv[4][8];
  #pragma unroll
  for (int j = 0; j < 4; j++) {
    int col = w * 64 + j * 16 + l15;
    colj[j] = col;
    binv[j] = ldx(b_in, col, isf);
    gv[j]   = ldx(g_in, col, isf);
    bev[j]  = ldx(be_in, col, isf);
    float4 a0 = *(const float4*)(u_in + (size_t)(b * 512 + col) * 8);
    float4 a1 = *(const float4*)(u_in + (size_t)(b * 512 + col) * 8 + 4);
    uv[j][0]=a0.x; uv[j][1]=a0.y; uv[j][2]=a0.z; uv[j][3]=a0.w;
    uv[j][4]=a1.x; uv[j][5]=a1.y; uv[j][6]=a1.z; uv[j][7]=a1.w;
  }

  for (int tile = 0; tile < 4; tile++) {
    int row0 = (blk * 4 + tile) * 64;
    size_t memBase = ((size_t)b * 4096 + row0) * 512;

    f32x4 acc[4][4];
    #pragma unroll
    for (int i = 0; i < 4; i++)
      #pragma unroll
      for (int j = 0; j < 4; j++) { acc[i][j][0]=0.f; acc[i][j][1]=0.f; acc[i][j][2]=0.f; acc[i][j][3]=0.f; }

    for (int kk = 0; kk < 512; kk += 32) {
      __syncthreads();   // orders prev-phase LDS reads before overwrite
      if (isf) {         // A tile 64x32 f32: 512 thr x 4 floats
        int e = t * 4;
        int r = e >> 5, c = e & 31;
        float4 v = *(const float4*)((const float*)mem + memBase + (size_t)r * 512 + kk + c);
        union { u16 h[4]; uint2 u; } pk;
        pk.h[0] = f2b(v.x); pk.h[1] = f2b(v.y); pk.h[2] = f2b(v.z); pk.h[3] = f2b(v.w);
        *(uint2*)(Ab + r * LDA + c) = pk.u;
      } else if (t < 256) {  // A tile 64x32 bf16: 256 thr x 8
        int r = t >> 2, ch = t & 3;
        uint4 v = *(const uint4*)((const u16*)mem + memBase + (size_t)r * 512 + kk + ch * 8);
        *(uint4*)(Ab + r * LDA + ch * 8) = v;
      }
      #pragma unroll
      for (int s2 = 0; s2 < 4; s2++) {  // B tile: 512 cols x 32 k (WT bf16 row-major)
        int e = t + 512 * s2;
        int j = e >> 2, ch = e & 3;
        uint4 v = *(const uint4*)(WT + (size_t)j * 512 + kk + ch * 8);
        *(uint4*)(Bb + j * LDB + ch * 8) = v;
      }
      __syncthreads();
      bf16x8 aF[4], bF[4];
      #pragma unroll
      for (int i = 0; i < 4; i++)
        aF[i] = *(const bf16x8*)(Ab + (i * 16 + l15) * LDA + q * 8);
      #pragma unroll
      for (int j = 0; j < 4; j++)
        bF[j] = *(const bf16x8*)(Bb + (w * 64 + j * 16 + l15) * LDB + q * 8);
      #pragma unroll
      for (int i = 0; i < 4; i++)
        #pragma unroll
        for (int j = 0; j < 4; j++)
          acc[i][j] = __builtin_amdgcn_mfma_f32_16x16x32_bf16(aF[i], bF[j], acc[i][j], 0, 0, 0);
    }
    __syncthreads();   // Bb dead; epilogue overlays begin

    // bias + relu
    #pragma unroll
    for (int i = 0; i < 4; i++)
      #pragma unroll
      for (int j = 0; j < 4; j++)
        #pragma unroll
        for (int r = 0; r < 4; r++) {
          float v = acc[i][j][r] + binv[j];
          acc[i][j][r] = v > 0.f ? v : 0.f;
        }
    // LN stats
    #pragma unroll
    for (int i = 0; i < 4; i++)
      #pragma unroll
      for (int r = 0; r < 4; r++) {
        float s  = acc[i][0][r] + acc[i][1][r] + acc[i][2][r] + acc[i][3][r];
        float ss = acc[i][0][r]*acc[i][0][r] + acc[i][1][r]*acc[i][1][r]
                 + acc[i][2][r]*acc[i][2][r] + acc[i][3][r]*acc[i][3][r];
        #pragma unroll
        for (int m = 1; m < 16; m <<= 1) { s += __shfl_xor(s, m); ss += __shfl_xor(ss, m); }
        if (l15 == 0) {
          int row = i * 16 + q * 4 + r;
          rowred[(w * 64 + row) * 2]     = s;
          rowred[(w * 64 + row) * 2 + 1] = ss;
        }
      }
    __syncthreads();
    if (t < 64) {
      float S = 0.f, SS = 0.f;
      for (int w2 = 0; w2 < 8; w2++) { S += rowred[(w2 * 64 + t) * 2]; SS += rowred[(w2 * 64 + t) * 2 + 1]; }
      float mu = S / 512.f;
      float var = SS / 512.f - mu * mu;
      mu_rstd[t * 2] = mu;
      mu_rstd[t * 2 + 1] = rsqrtf(var + 1e-5f);
    }
    __syncthreads();
    // apply LN
    #pragma unroll
    for (int i = 0; i < 4; i++)
      #pragma unroll
      for (int r = 0; r < 4; r++) {
        int row = i * 16 + q * 4 + r;
        float mu = mu_rstd[row * 2], rstd = mu_rstd[row * 2 + 1];
        #pragma unroll
        for (int j = 0; j < 4; j++)
          acc[i][j][r] = (acc[i][j][r] - mu) * rstd * gv[j] + bev[j];
      }

    // scores: per-row per-head partials over this wave's 64 cols
    #pragma unroll
    for (int i = 0; i < 4; i++)
      #pragma unroll
      for (int r = 0; r < 4; r++) {
        int row = i * 16 + q * 4 + r;
        float p[8];
        #pragma unroll
        for (int n = 0; n < 8; n++) {
          float v = acc[i][0][r]*uv[0][n] + acc[i][1][r]*uv[1][n]
                  + acc[i][2][r]*uv[2][n] + acc[i][3][r]*uv[3][n];
          #pragma unroll
          for (int m = 1; m < 16; m <<= 1) v += __shfl_xor(v, m);
          p[n] = v;
        }
        if (l15 == 0) {
          *(float4*)(sc + (w * 64 + row) * 8)     = make_float4(p[0], p[1], p[2], p[3]);
          *(float4*)(sc + (w * 64 + row) * 8 + 4) = make_float4(p[4], p[5], p[6], p[7]);
        }
      }
    __syncthreads();

    // a[row][n] = (sum_w sc + c0) * scale * ior
    {
      int row = t >> 3, n = t & 7;
      float ssum = 0.f;
      #pragma unroll
      for (int w2 = 0; w2 < 8; w2++) ssum += sc[(w2 * 64 + row) * 8 + n];
      float aval = (ssum + c0_in[b * 8 + n]) * 0.125f
                 * ldx(ior, ((size_t)b * 8 + n) * 4096 + row0 + row, isf);
      a_lds[row * 8 + n] = aval;
    }
    __syncthreads();

    if (t < 8) {
      float s = 0.f;
      for (int row = 0; row < 64; row++) s += a_lds[row * 8 + t];
      A_l[t] += s;
    }

    // r[n][col] contribution of this tile's 64 rows
    float rv[4][8];
    #pragma unroll
    for (int j = 0; j < 4; j++)
      #pragma unroll
      for (int n = 0; n < 8; n++) rv[j][n] = 0.f;
    #pragma unroll
    for (int i = 0; i < 4; i++)
      #pragma unroll
      for (int r = 0; r < 4; r++) {
        int row = i * 16 + q * 4 + r;
        const float* ap = a_lds + row * 8;
        float a0=ap[0],a1=ap[1],a2=ap[2],a3=ap[3],a4=ap[4],a5=ap[5],a6=ap[6],a7=ap[7];
        #pragma unroll
        for (int j = 0; j < 4; j++) {
          float m = acc[i][j][r];
          rv[j][0] += m*a0; rv[j][1] += m*a1; rv[j][2] += m*a2; rv[j][3] += m*a3;
          rv[j][4] += m*a4; rv[j][5] += m*a5; rv[j][6] += m*a6; rv[j][7] += m*a7;
        }
      }
    #pragma unroll
    for (int j = 0; j < 4; j++)
      #pragma unroll
      for (int n = 0; n < 8; n++) {
        float v = rv[j][n];
        v += __shfl_xor(v, 16);
        v += __shfl_xor(v, 32);
        rv[j][n] = v;
      }
    if (q == 0) {   // wave-exclusive cols -> race-free LDS accumulate
      #pragma unroll
      for (int j = 0; j < 4; j++)
        #pragma unroll
        for (int n = 0; n < 8; n++)
          r_lds[n * 512 + colj[j]] += rv[j][n];
    }
  }
  __syncthreads();

  // per-block V matvec -> atomic into x_acc
  {
    int j = t, n = t >> 6;
    float s = A_l[n] * ldx(bkv, 512 + j, isf);
    const float* rl = r_lds + n * 512;
    if (isf) {
      const float* wv = (const float*)Wkv + 512 + j;
      #pragma unroll 8
      for (int c = 0; c < 512; c++) s += rl[c] * wv[(size_t)c * 1024];
    } else {
      const u16* wv = (const u16*)Wkv + 512 + j;
      #pragma unroll 8
      for (int c = 0; c < 512; c++) s += rl[c] * b2f(wv[(size_t)c * 1024]);
    }
    atomicAdd(x_acc + (size_t)b * 512 + j, s);
  }
}

// ---------------- kernel 4: xrow = x_acc + query; LN -> xln ----------------
__global__ __launch_bounds__(512) void k_mid(
    const float* __restrict__ x_acc, const void* __restrict__ query,
    const void* __restrict__ g_f, const void* __restrict__ be_f,
    float* __restrict__ xrow_ws, float* __restrict__ xln_ws,
    const int* __restrict__ flag) {
  int isf = flag[0];
  int b = blockIdx.x, t = threadIdx.x;
  __shared__ float red[16];
  __shared__ float stats[2];
  float v = x_acc[(size_t)b * 512 + t] + ldx(query, (size_t)b * 512 + t, isf);
  xrow_ws[(size_t)b * 512 + t] = v;
  float s1 = v, s2 = v * v;
  for (int off = 32; off; off >>= 1) { s1 += __shfl_xor(s1, off); s2 += __shfl_xor(s2, off); }
  int wid = t >> 6, lane = t & 63;
  if (lane == 0) { red[wid * 2] = s1; red[wid * 2 + 1] = s2; }
  __syncthreads();
  if (t == 0) {
    float S = 0.f, SS = 0.f;
    for (int w = 0; w < 8; w++) { S += red[w * 2]; SS += red[w * 2 + 1]; }
    float mu = S / 512.f;
    float var = SS / 512.f - mu * mu;
    stats[0] = mu; stats[1] = rsqrtf(var + 1e-5f);
  }
  __syncthreads();
  xln_ws[(size_t)b * 512 + t] = (v - stats[0]) * stats[1] * ldx(g_f, t, isf) + ldx(be_f, t, isf);
}

// ---------------- kernel 5: hdn = gelu(xln @ W1 + b1) ----------------
__global__ __launch_bounds__(512) void k_ffn1(
    const float* __restrict__ xln_ws, const void* __restrict__ W1, const void* __restrict__ b1,
    float* __restrict__ hdn_ws, const int* __restrict__ flag) {
  int isf = flag[0];
  int jb = blockIdx.x, b = blockIdx.y, t = threadIdx.x;
  __shared__ float xl[512];
  xl[t] = xln_ws[(size_t)b * 512 + t];
  __syncthreads();
  int j = jb * 512 + t;
  float acc = ldx(b1, j, isf);
  if (isf) {
    const float* wp = (const float*)W1 + j;
    #pragma unroll 8
    for (int c = 0; c < 512; c++) acc += xl[c] * wp[(size_t)c * 2048];
  } else {
    const u16* wp = (const u16*)W1 + j;
    #pragma unroll 8
    for (int c = 0; c < 512; c++) acc += xl[c] * b2f(wp[(size_t)c * 2048]);
  }
  hdn_ws[(size_t)b * 2048 + j] = 0.5f * acc * (1.0f + erff(acc * 0.70710678118654752f));
}

// ---------------- kernel 6: y_acc += hdn_slice @ W2_slice ----------------
__global__ __launch_bounds__(512) void k_ffn2(
    const float* __restrict__ hdn_ws, const void* __restrict__ W2,
    float* __restrict__ y_acc, const int* __restrict__ flag) {
  int isf = flag[0];
  int cb = blockIdx.x, b = blockIdx.y, t = threadIdx.x;
  __shared__ float hl[512];
  hl[t] = hdn_ws[(size_t)b * 2048 + cb * 512 + t];
  __syncthreads();
  int j = t;
  float acc = 0.f;
  if (isf) {
    const float* wp = (const float*)W2 + (size_t)cb * 512 * 512 + j;
    #pragma unroll 8
    for (int c = 0; c < 512; c++) acc += hl[c] * wp[(size_t)c * 512];
  } else {
    const u16* wp = (const u16*)W2 + (size_t)cb * 512 * 512 + j;
    #pragma unroll 8
    for (int c = 0; c < 512; c++) acc += hl[c] * b2f(wp[(size_t)c * 512]);
  }
  atomicAdd(y_acc + (size_t)b * 512 + j, acc);
}

// ---------------- kernel 7: out = cast(y_acc + b2 + xrow) ----------------
__global__ __launch_bounds__(512) void k_final(
    const float* __restrict__ y_acc, const void* __restrict__ b2v,
    const float* __restrict__ xrow_ws, void* __restrict__ out,
    const int* __restrict__ flag) {
  int isf = flag[0];
  int b = blockIdx.x, t = threadIdx.x;
  float v = y_acc[(size_t)b * 512 + t] + ldx(b2v, t, isf) + xrow_ws[(size_t)b * 512 + t];
  if (isf) ((float*)out)[b * 512 + t] = v;
  else     ((u16*)out)[b * 512 + t] = f2b(v);
}

extern "C" void kernel_launch(void* const* d_in, const int* in_sizes, int n_in,
                              void* d_out, int out_size, void* d_ws, size_t ws_size,
                              hipStream_t stream) {
  const void* query = d_in[0];
  const void* mem   = d_in[1];
  const void* ior   = d_in[2];
  const void* W_in  = d_in[3];
  const void* b_in  = d_in[4];
  const void* g_in  = d_in[5];
  const void* be_in = d_in[6];
  const void* Wq    = d_in[7];
  const void* bq    = d_in[8];
  const void* Wkv   = d_in[9];
  const void* bkv   = d_in[10];
  const void* W1    = d_in[11];
  const void* b1    = d_in[12];
  const void* W2    = d_in[13];
  const void* b2v   = d_in[14];
  const void* g_q   = d_in[15];
  const void* be_q  = d_in[16];
  const void* g_f   = d_in[17];
  const void* be_f  = d_in[18];

  // ws layout (total 1,574,144 B)
  char* ws = (char*)d_ws;
  int*   flag   = (int*)ws;                     // 256
  float* u_ws   = (float*)(ws + 256);           // 524288
  float* c0_ws  = (float*)(ws + 524544);        // 1024
  float* x_acc  = (float*)(ws + 525568);        // 65536
  float* y_acc  = (float*)(ws + 591104);        // 65536
  float* xrow_ws= (float*)(ws + 656640);        // 65536
  float* xln_ws = (float*)(ws + 722176);        // 65536
  float* hdn_ws = (float*)(ws + 787712);        // 262144
  u16*   WT     = (u16*)(ws + 1049856);         // 524288

  hipMemsetAsync(ws + 525568, 0, 131072, stream);  // zero x_acc + y_acc
  k_detect<<<dim3(1), dim3(64), 0, stream>>>(query, flag);
  k_transpose<<<dim3(1024), dim3(256), 0, stream>>>(W_in, WT, flag);
  k_qprep<<<dim3(32), dim3(256), 0, stream>>>(query, Wq, bq, Wkv, bkv, g_q, be_q,
                                              u_ws, c0_ws, flag);
  k_main<<<dim3(16, 32), dim3(512), 0, stream>>>(mem, WT, b_in, g_in, be_in, ior,
                                                 u_ws, c0_ws, Wkv, bkv, x_acc, flag);
  k_mid<<<dim3(32), dim3(512), 0, stream>>>(x_acc, query, g_f, be_f, xrow_ws, xln_ws, flag);
  k_ffn1<<<dim3(4, 32), dim3(512), 0, stream>>>(xln_ws, W1, b1, hdn_ws, flag);
  k_ffn2<<<dim3(4, 32), dim3(512), 0, stream>>>(hdn_ws, W2, y_acc, flag);
  k_final<<<dim3(32), dim3(512), 0, stream>>>(y_acc, b2v, xrow_ws, d_out, flag);
}